// Round 5
// baseline (895.002 us; speedup 1.0000x reference)
//
#include <hip/hip_runtime.h>
#include <stdint.h>

#define B_ 512
#define D_ 512
#define C_ 100000
#define CK_ 300000
#define S_ 30.0f
#define COSM_ 0.8775825618903728f
#define SINM_ 0.4794255386042030f
#define TH_ (-0.8775825618903728f)
#define MM_ 0.2397127693021015f
#define EPS_ 1e-12f

#define BM 128
#define BN 96

typedef float f32x4 __attribute__((ext_vector_type(4)));
typedef short s16x8 __attribute__((ext_vector_type(8)));
typedef unsigned long long u64;
typedef unsigned int u32;

__device__ __forceinline__ unsigned short f2bf(float f){
  u32 u = __float_as_uint(f);
  u += 0x7FFFu + ((u >> 16) & 1u);
  return (unsigned short)(u >> 16);
}

// ---------------- normalize x rows -> unit bf16 ----------------
__global__ void k_normx(const float* __restrict__ x, unsigned short* __restrict__ xn){
  int row  = blockIdx.x * 4 + (threadIdx.x >> 6);
  int lane = threadIdx.x & 63;
  const float* xr = x + (size_t)row * D_ + lane * 8;
  float4 v0 = *(const float4*)xr;
  float4 v1 = *(const float4*)(xr + 4);
  float s = v0.x*v0.x + v0.y*v0.y + v0.z*v0.z + v0.w*v0.w
          + v1.x*v1.x + v1.y*v1.y + v1.z*v1.z + v1.w*v1.w;
  #pragma unroll
  for (int off = 1; off < 64; off <<= 1) s += __shfl_xor(s, off);
  float inv = 1.f / fmaxf(sqrtf(s), EPS_);
  s16x8 h;
  h[0] = (short)f2bf(v0.x*inv); h[1] = (short)f2bf(v0.y*inv);
  h[2] = (short)f2bf(v0.z*inv); h[3] = (short)f2bf(v0.w*inv);
  h[4] = (short)f2bf(v1.x*inv); h[5] = (short)f2bf(v1.y*inv);
  h[6] = (short)f2bf(v1.z*inv); h[7] = (short)f2bf(v1.w*inv);
  *(s16x8*)(xn + (size_t)row * D_ + lane * 8) = h;
}

// ---------------- zero the per-row reduction buffers ----------------
__global__ void k_init(float* __restrict__ sumexp, u64* __restrict__ packed,
                       float* __restrict__ phi){
  int i = threadIdx.x;
  sumexp[i] = 0.f;
  packed[i] = 0ull;
  phi[i]    = 0.f;
}

// ======= fused GEMM: all operands register-resident, NO main-loop LDS =======
__global__ __launch_bounds__(256, 3) void k_gemm3(
    const unsigned short* __restrict__ xn, const float* __restrict__ w,
    const int* __restrict__ label,
    float* __restrict__ sumexp_g, u64* __restrict__ packed_g,
    float* __restrict__ phi_g)
{
  __shared__ float mx[BM*33];
  __shared__ int   slab[BM];

  // bijective XCD-chunked mapping (12500 blocks, 8 XCDs: q=1562, r=4):
  // the 4 row-tiles sharing one weight column-tile run consecutively on ONE XCD.
  const int bid = blockIdx.x;
  const int xcd = bid & 7;
  const int i8  = bid >> 3;
  const int seq = (xcd < 4) ? (xcd*1563 + i8) : (6252 + (xcd-4)*1562 + i8);
  const int ct = seq >> 2;                 // column tile 0..3124
  const int rt = seq & 3;                  // row tile 0..3
  const int rowbase = rt * BM;
  const int colbase = ct * BN;

  const int tid  = threadIdx.x;
  const int lane = tid & 63;
  const int wid  = tid >> 6;
  const int wm   = wid >> 1, wn = wid & 1; // 2x2 wave grid, wave tile 64x48
  const int lc15 = lane & 15, lhi = lane >> 4;

  if (tid < BM) slab[tid] = label[rowbase + tid];

  // A fragment source: row = rowbase + wm*64 + m*16 + lc15, k-slice lhi*8 (bf16)
  const unsigned short* aptr[4];
  #pragma unroll
  for (int m = 0; m < 4; ++m)
    aptr[m] = xn + (size_t)(rowbase + wm*64 + m*16 + lc15) * D_ + lhi*8;

  // B fragment source: subcenter n of class (wn*16 + lc15), fp32, k-slice lhi*8
  const float* bptr[3];
  #pragma unroll
  for (int n = 0; n < 3; ++n)
    bptr[n] = w + (size_t)(colbase + (wn*16 + lc15)*3 + n) * D_ + lhi*8;

  f32x4 acc[4][3] = {};
  float sq[3] = {0.f, 0.f, 0.f};

  #pragma unroll
  for (int kt = 0; kt < 16; ++kt){         // BK = 32 per step
    const int k0 = kt * 32;
    // A: 4 x b128 (bf16 fragments, ready to use)
    s16x8 af[4];
    #pragma unroll
    for (int m = 0; m < 4; ++m) af[m] = *(const s16x8*)(aptr[m] + k0);
    // B: 3 x 32B fp32, accumulate sumsq, convert packed to bf16
    s16x8 bfr[3];
    #pragma unroll
    for (int n = 0; n < 3; ++n){
      float4 v0 = *(const float4*)(bptr[n] + k0);
      float4 v1 = *(const float4*)(bptr[n] + k0 + 4);
      sq[n] += v0.x*v0.x + v0.y*v0.y + v0.z*v0.z + v0.w*v0.w
             + v1.x*v1.x + v1.y*v1.y + v1.z*v1.z + v1.w*v1.w;
      union { s16x8 h; u32 u[4]; } pk;
      asm("v_cvt_pk_bf16_f32 %0, %1, %2" : "=v"(pk.u[0]) : "v"(v0.x), "v"(v0.y));
      asm("v_cvt_pk_bf16_f32 %0, %1, %2" : "=v"(pk.u[1]) : "v"(v0.z), "v"(v0.w));
      asm("v_cvt_pk_bf16_f32 %0, %1, %2" : "=v"(pk.u[2]) : "v"(v1.x), "v"(v1.y));
      asm("v_cvt_pk_bf16_f32 %0, %1, %2" : "=v"(pk.u[3]) : "v"(v1.z), "v"(v1.w));
      bfr[n] = pk.h;
    }
    #pragma unroll
    for (int m = 0; m < 4; ++m)
      #pragma unroll
      for (int n = 0; n < 3; ++n)
        acc[m][n] = __builtin_amdgcn_mfma_f32_16x16x32_bf16(af[m], bfr[n], acc[m][n], 0, 0, 0);
  }

  // full row sumsq: this lane holds the lhi-slice partial; fold across lhi lanes
  float inv[3];
  #pragma unroll
  for (int n = 0; n < 3; ++n){
    float s = sq[n];
    s += __shfl_xor(s, 16);
    s += __shfl_xor(s, 32);
    inv[n] = 1.f / fmaxf(sqrtf(s), EPS_);
  }

  __syncthreads();   // slab ready; mx about to be written

  // subcenter max in-register (3 n-frags = 3 subcenters of class wn*16+lc15)
  {
    int cls    = wn*16 + lc15;
    int lcbase = ct * 32;
    #pragma unroll
    for (int m = 0; m < 4; ++m){
      #pragma unroll
      for (int r = 0; r < 4; ++r){
        int rl = wm*64 + m*16 + lhi*4 + r;
        float v = fmaxf(fmaxf(acc[m][0][r]*inv[0], acc[m][1][r]*inv[1]), acc[m][2][r]*inv[2]);
        if (slab[rl] - lcbase == cls){
          float cy = v;
          float s2 = fminf(fmaxf(1.f - cy*cy, 0.f), 1.f);
          float sy = sqrtf(s2);
          float ph = cy*COSM_ - sy*SINM_;
          if (!(cy - TH_ > 0.f)) ph = cy - MM_;
          phi_g[rowbase + rl] = ph;        // unique writer
          v = ph;
        }
        mx[rl*33 + cls] = v;
      }
    }
  }
  __syncthreads();

  // per-row LSE + argmax over this block's 32 classes: 2 threads per row
  {
    int row  = tid >> 1;
    int half = tid & 1;
    int grow = rowbase + row;
    float se = 0.f;
    u64 pk = 0ull;
    #pragma unroll
    for (int c = 0; c < 16; ++c){
      int lc = half*16 + c;
      float v = mx[row*33 + lc];
      se += __expf(S_*v - S_);
      u32 u = __float_as_uint(v);
      u = (v >= 0.f) ? (u | 0x80000000u) : ~u;            // sortable float
      u64 p = ((u64)u << 32) | (u32)~(u32)(ct*32 + lc);   // ~idx: first-occurrence ties
      pk = (p > pk) ? p : pk;
    }
    se += __shfl_xor(se, 1);
    u32 lo = (u32)pk, hi = (u32)(pk >> 32);
    u32 plo = __shfl_xor(lo, 1), phi2 = __shfl_xor(hi, 1);
    u64 po = ((u64)phi2 << 32) | plo;
    pk = (po > pk) ? po : pk;
    if (half == 0){
      atomicAdd(&sumexp_g[grow], se);
      atomicMax(&packed_g[grow], pk);
    }
  }
}

// ---------------- finalize: loss + prec1 ----------------
__global__ void k_final(const float* __restrict__ sumexp, const u64* __restrict__ packed,
                        const float* __restrict__ phi, const int* __restrict__ label,
                        float* __restrict__ out){
  int i = threadIdx.x;
  float lse  = S_ + logf(sumexp[i]);
  float loss = lse - S_ * phi[i];
  u32 pred = ~(u32)(packed[i] & 0xFFFFFFFFull);
  float corr = (pred == (u32)label[i]) ? 1.f : 0.f;
  float a = loss, b = corr;
  #pragma unroll
  for (int off = 1; off < 64; off <<= 1){ a += __shfl_xor(a, off); b += __shfl_xor(b, off); }
  __shared__ float sa[8], sb[8];
  if ((i & 63) == 0){ sa[i >> 6] = a; sb[i >> 6] = b; }
  __syncthreads();
  if (i == 0){
    float ta = 0.f, tb = 0.f;
    #pragma unroll
    for (int j = 0; j < 8; ++j){ ta += sa[j]; tb += sb[j]; }
    out[0] = ta / 512.f;
    out[1] = tb * (100.f / 512.f);
  }
}

extern "C" void kernel_launch(void* const* d_in, const int* in_sizes, int n_in,
                              void* d_out, int out_size, void* d_ws, size_t ws_size,
                              hipStream_t stream){
  const float* x     = (const float*)d_in[0];
  const int*   label = (const int*)d_in[1];
  const float* w     = (const float*)d_in[2];
  float* out = (float*)d_out;
  char* ws = (char*)d_ws;

  unsigned short* xn = (unsigned short*)ws;            // 524288 B
  float* sumexp = (float*)(ws + 524288);               // 2048 B
  u64*   packed = (u64*)(ws + 524288 + 2048);          // 4096 B
  float* phi    = (float*)(ws + 524288 + 2048 + 4096); // 2048 B

  k_init <<<1,   512, 0, stream>>>(sumexp, packed, phi);
  k_normx<<<B_/4, 256, 0, stream>>>(x, xn);
  k_gemm3<<<(CK_/BN)*4, 256, 0, stream>>>(xn, w, label, sumexp, packed, phi);
  k_final<<<1,   512, 0, stream>>>(sumexp, packed, phi, label, out);
}

// Round 6
// 409.623 us; speedup vs baseline: 2.1849x; 2.1849x over previous
//
#include <hip/hip_runtime.h>
#include <stdint.h>

#define B_ 512
#define D_ 512
#define C_ 100000
#define CK_ 300000
#define S_ 30.0f
#define COSM_ 0.8775825618903728f
#define SINM_ 0.4794255386042030f
#define TH_ (-0.8775825618903728f)
#define MM_ 0.2397127693021015f
#define EPS_ 1e-12f

#define BM 128
#define BN 96
#define BK 64
#define BUFU (BM*BK + BN*BK)   /* ushorts per LDS buffer = 14336 */

typedef float f32x4 __attribute__((ext_vector_type(4)));
typedef short s16x8 __attribute__((ext_vector_type(8)));
typedef unsigned long long u64;
typedef unsigned int u32;

#define GLL16(g, l) __builtin_amdgcn_global_load_lds( \
    (const __attribute__((address_space(1))) void*)(g), \
    (__attribute__((address_space(3))) void*)(l), 16, 0, 0)

__device__ __forceinline__ unsigned short f2bf(float f){
  u32 u = __float_as_uint(f);
  u += 0x7FFFu + ((u >> 16) & 1u);
  return (unsigned short)(u >> 16);
}

// ---------------- normalize rows of [nrows, 512] fp32 -> unit bf16 ----------------
__global__ void k_norm(const float* __restrict__ src, unsigned short* __restrict__ dst){
  int row  = blockIdx.x * 4 + (threadIdx.x >> 6);
  int lane = threadIdx.x & 63;
  const float* r = src + (size_t)row * D_ + lane * 8;
  float4 v0 = *(const float4*)r;
  float4 v1 = *(const float4*)(r + 4);
  float s = v0.x*v0.x + v0.y*v0.y + v0.z*v0.z + v0.w*v0.w
          + v1.x*v1.x + v1.y*v1.y + v1.z*v1.z + v1.w*v1.w;
  #pragma unroll
  for (int off = 1; off < 64; off <<= 1) s += __shfl_xor(s, off);
  float inv = 1.f / fmaxf(sqrtf(s), EPS_);
  s16x8 h;
  h[0] = (short)f2bf(v0.x*inv); h[1] = (short)f2bf(v0.y*inv);
  h[2] = (short)f2bf(v0.z*inv); h[3] = (short)f2bf(v0.w*inv);
  h[4] = (short)f2bf(v1.x*inv); h[5] = (short)f2bf(v1.y*inv);
  h[6] = (short)f2bf(v1.z*inv); h[7] = (short)f2bf(v1.w*inv);
  *(s16x8*)(dst + (size_t)row * D_ + lane * 8) = h;
}

// ---------------- zero the per-row reduction buffers ----------------
__global__ void k_init(float* __restrict__ sumexp, u64* __restrict__ packed,
                       float* __restrict__ phi){
  int i = threadIdx.x;
  sumexp[i] = 0.f;
  packed[i] = 0ull;
  phi[i]    = 0.f;
}

// ======= PATH A: pipelined bf16 GEMM, DMA staging, st_16x32 swizzle =======
__global__ __launch_bounds__(256, 2) void k_gemm4(
    const unsigned short* __restrict__ xn, const unsigned short* __restrict__ wnb,
    const int* __restrict__ label,
    float* __restrict__ sumexp_g, u64* __restrict__ packed_g,
    float* __restrict__ phi_g)
{
  __shared__ unsigned short st[2*BUFU];   // double-buffered A|B tiles, linear 128B rows
  __shared__ int slab[BM];
  float* mx = (float*)st;                 // epilogue overlay: [BM][33]

  // bijective XCD-chunked mapping (12500 blocks, 8 XCDs: q=1562, r=4)
  const int bid = blockIdx.x;
  const int xcd = bid & 7;
  const int i8  = bid >> 3;
  const int seq = (xcd < 4) ? (xcd*1563 + i8) : (6252 + (xcd-4)*1562 + i8);
  const int ct = seq >> 2;                 // column tile 0..3124
  const int rt = seq & 3;                  // row tile 0..3
  const int rowbase = rt * BM;
  const int colbase = ct * BN;

  const int tid  = threadIdx.x;
  const int lane = tid & 63;
  const int wid  = tid >> 6;
  const int wm   = wid >> 1, wn = wid & 1; // 2x2 wave grid, wave tile 64x48
  const int lc15 = lane & 15, lhi = lane >> 4;

  if (tid < BM) slab[tid] = label[rowbase + tid];

  // ---- st_16x32 (m201): 16B-slot ^= ((row>>2)&1)<<1, rows are 128B.
  // DMA writes LINEAR (byte = p*4096 + tid*16); global source is pre-swizzled.
  // staging row for pass p: p*32 + (tid>>3); (row>>2)&1 == (tid>>5)&1 (p*32 has bit2=0)
  const int slotg = (tid & 7) ^ (((tid >> 5) & 1) << 1);
  const unsigned short* asrc[4];
  #pragma unroll
  for (int p = 0; p < 4; ++p){
    int row = p*32 + (tid >> 3);
    asrc[p] = xn + (size_t)(rowbase + row) * D_ + slotg*8;
  }
  const unsigned short* bsrc[3];
  #pragma unroll
  for (int p = 0; p < 3; ++p){
    int pos = p*32 + (tid >> 3);           // permuted tile position 0..95
    int wnp = pos / 48, rem = pos % 48;
    int j = rem >> 4, c = rem & 15;        // subcenter j of class (wnp*16+c)
    int wrow = colbase + (wnp*16 + c)*3 + j;
    bsrc[p] = wnb + (size_t)wrow * D_ + slotg*8;
  }

  // ---- fragment read offsets (ushort units), same involution on read ----
  const int sw = ((lc15 >> 2) & 1) << 1;
  int aoff[4][2], boff[3][2];
  #pragma unroll
  for (int m = 0; m < 4; ++m){
    int row = wm*64 + m*16 + lc15;
    #pragma unroll
    for (int ks = 0; ks < 2; ++ks)
      aoff[m][ks] = row*BK + (((ks*4 + lhi) ^ sw) << 3);
  }
  #pragma unroll
  for (int n = 0; n < 3; ++n){
    int pos = wn*48 + n*16 + lc15;
    #pragma unroll
    for (int ks = 0; ks < 2; ++ks)
      boff[n][ks] = BM*BK + pos*BK + (((ks*4 + lhi) ^ sw) << 3);
  }

  f32x4 acc[4][3] = {};

  // ---- prologue: stage tile 0 into buffer 0 ----
  #pragma unroll
  for (int p = 0; p < 4; ++p) GLL16(asrc[p], &st[p*2048 + tid*8]);
  #pragma unroll
  for (int p = 0; p < 3; ++p) GLL16(bsrc[p], &st[BM*BK + p*2048 + tid*8]);

  // ---- main loop: prefetch(t+1) -> counted vmcnt -> barrier -> compute(t) -> barrier
  #pragma unroll
  for (int t = 0; t < 8; ++t){
    const int cur = t & 1;
    if (t < 7){
      const int k0 = (t+1)*BK;
      unsigned short* nb = &st[(cur^1)*BUFU];
      #pragma unroll
      for (int p = 0; p < 4; ++p) GLL16(asrc[p] + k0, nb + p*2048 + tid*8);
      #pragma unroll
      for (int p = 0; p < 3; ++p) GLL16(bsrc[p] + k0, nb + BM*BK + p*2048 + tid*8);
      asm volatile("s_waitcnt vmcnt(7)" ::: "memory");   // own tile-t loads landed
    } else {
      asm volatile("s_waitcnt vmcnt(0)" ::: "memory");
    }
    __builtin_amdgcn_s_barrier();                        // all waves' tile-t data visible
    asm volatile("" ::: "memory");
    const unsigned short* cb = &st[cur*BUFU];
    #pragma unroll
    for (int ks = 0; ks < 2; ++ks){
      s16x8 af[4], bfr[3];
      #pragma unroll
      for (int m = 0; m < 4; ++m) af[m]  = *(const s16x8*)(cb + aoff[m][ks]);
      #pragma unroll
      for (int n = 0; n < 3; ++n) bfr[n] = *(const s16x8*)(cb + boff[n][ks]);
      #pragma unroll
      for (int m = 0; m < 4; ++m)
        #pragma unroll
        for (int n = 0; n < 3; ++n)
          acc[m][n] = __builtin_amdgcn_mfma_f32_16x16x32_bf16(af[m], bfr[n], acc[m][n], 0, 0, 0);
    }
    asm volatile("" ::: "memory");
    __builtin_amdgcn_s_barrier();                        // done reading buf[cur]
  }

  __syncthreads();   // full drain before mx overlays the staging buffers

  // acc IS cosine. Subcenter max in-register (3 n-frags = 3 subcenters of one class).
  {
    int cls    = wn*16 + lc15;
    int lcbase = ct * 32;
    #pragma unroll
    for (int m = 0; m < 4; ++m){
      #pragma unroll
      for (int r = 0; r < 4; ++r){
        int rl = wm*64 + m*16 + lhi*4 + r;
        float v = fmaxf(fmaxf(acc[m][0][r], acc[m][1][r]), acc[m][2][r]);
        if (slab[rl] - lcbase == cls){
          float cy = v;
          float s2 = fminf(fmaxf(1.f - cy*cy, 0.f), 1.f);
          float sy = sqrtf(s2);
          float ph = cy*COSM_ - sy*SINM_;
          if (!(cy - TH_ > 0.f)) ph = cy - MM_;
          phi_g[rowbase + rl] = ph;        // unique writer
          v = ph;
        }
        mx[rl*33 + cls] = v;
      }
    }
  }
  __syncthreads();

  // per-row LSE + argmax over this block's 32 classes: 2 threads per row
  {
    int row  = tid >> 1;
    int half = tid & 1;
    int grow = rowbase + row;
    float se = 0.f;
    u64 pk = 0ull;
    #pragma unroll
    for (int c = 0; c < 16; ++c){
      int lc = half*16 + c;
      float v = mx[row*33 + lc];
      se += __expf(S_*v - S_);
      u32 u = __float_as_uint(v);
      u = (v >= 0.f) ? (u | 0x80000000u) : ~u;            // sortable float
      u64 p = ((u64)u << 32) | (u32)~(u32)(ct*32 + lc);   // ~idx: first-occurrence ties
      pk = (p > pk) ? p : pk;
    }
    se += __shfl_xor(se, 1);
    u32 lo = (u32)pk, hi = (u32)(pk >> 32);
    u32 plo = __shfl_xor(lo, 1), phi2 = __shfl_xor(hi, 1);
    u64 po = ((u64)phi2 << 32) | plo;
    pk = (po > pk) ? po : pk;
    if (half == 0){
      atomicAdd(&sumexp_g[grow], se);
      atomicMax(&packed_g[grow], pk);
    }
  }
}

// ================= PATH B (fallback, ws too small): round-3 fused kernel =========
__global__ __launch_bounds__(256, 3) void k_gemm_fused(
    const unsigned short* __restrict__ xn, const float* __restrict__ w,
    const int* __restrict__ label,
    float* __restrict__ sumexp_g, u64* __restrict__ packed_g,
    float* __restrict__ phi_g)
{
  __shared__ union {
    struct { unsigned short a[BM*BK]; unsigned short b[BN*BK]; } st;
    float mx[BM*33];
  } sm;
  __shared__ float invs[BN];
  __shared__ int   slab[BM];

  const int bid = blockIdx.x;
  const int xcd = bid & 7;
  const int i8  = bid >> 3;
  const int seq = (xcd < 4) ? (xcd*1563 + i8) : (6252 + (xcd-4)*1562 + i8);
  const int ct = seq >> 2;
  const int rt = seq & 3;
  const int rowbase = rt * BM;
  const int colbase = ct * BN;

  const int tid  = threadIdx.x;
  const int lane = tid & 63;
  const int wid  = tid >> 6;
  const int wm   = wid >> 1, wn = wid & 1;
  const int lc15 = lane & 15, lhi = lane >> 4;

  if (tid < BM) slab[tid] = label[rowbase + tid];

  const int arow0 = tid >> 3, au = tid & 7;
  const unsigned short* asrc0 = xn + (size_t)(rowbase + arow0) * D_ + au * 8;
  const int adst0 = arow0 * BK + ((au * 8) ^ ((arow0 & 7) << 3));

  const int bc = tid >> 4, bu = tid & 15;
  const float* bsrc0 = w + (size_t)(colbase + bc * 3) * D_ + bu * 4;
  const int bdst0 = bc * BK + ((bu * 4) ^ ((bc & 7) << 3));

  const int swz = (lc15 & 7) << 3;
  int aoff[4][2], boff[3][2];
  #pragma unroll
  for (int m = 0; m < 4; ++m){
    int row = wm*64 + m*16 + lc15;
    #pragma unroll
    for (int ks = 0; ks < 2; ++ks) aoff[m][ks] = row * BK + ((ks*32 + lhi*8) ^ swz);
  }
  #pragma unroll
  for (int n = 0; n < 3; ++n){
    int row = wn*48 + n*16 + lc15;
    #pragma unroll
    for (int ks = 0; ks < 2; ++ks) boff[n][ks] = row * BK + ((ks*32 + lhi*8) ^ swz);
  }

  f32x4 acc[4][3] = {};
  float sq[6] = {0.f,0.f,0.f,0.f,0.f,0.f};

  for (int kt = 0; kt < D_/BK; ++kt){
    const int k0 = kt * BK;
    #pragma unroll
    for (int p = 0; p < 4; ++p){
      s16x8 v = *(const s16x8*)(asrc0 + (size_t)p*32*D_ + k0);
      *(s16x8*)(&sm.st.a[adst0 + p*32*BK]) = v;
    }
    #pragma unroll
    for (int p = 0; p < 6; ++p){
      float4 v = *(const float4*)(bsrc0 + (size_t)((p/3)*48 + (p%3)) * D_ + k0);
      sq[p] += v.x*v.x + v.y*v.y + v.z*v.z + v.w*v.w;
      ushort4 h;
      h.x = f2bf(v.x); h.y = f2bf(v.y); h.z = f2bf(v.z); h.w = f2bf(v.w);
      *(ushort4*)(&sm.st.b[bdst0 + p*16*BK]) = h;
    }
    __syncthreads();
    #pragma unroll
    for (int ks = 0; ks < 2; ++ks){
      s16x8 af[4], bfr[3];
      #pragma unroll
      for (int m = 0; m < 4; ++m) af[m]  = *(const s16x8*)(&sm.st.a[aoff[m][ks]]);
      #pragma unroll
      for (int n = 0; n < 3; ++n) bfr[n] = *(const s16x8*)(&sm.st.b[boff[n][ks]]);
      #pragma unroll
      for (int m = 0; m < 4; ++m)
        #pragma unroll
        for (int n = 0; n < 3; ++n)
          acc[m][n] = __builtin_amdgcn_mfma_f32_16x16x32_bf16(af[m], bfr[n], acc[m][n], 0, 0, 0);
    }
    __syncthreads();
  }

  #pragma unroll
  for (int p = 0; p < 6; ++p){
    float s = sq[p];
    s += __shfl_xor(s, 1); s += __shfl_xor(s, 2);
    s += __shfl_xor(s, 4); s += __shfl_xor(s, 8);
    if ((tid & 15) == 0) invs[p*16 + (tid >> 4)] = 1.f / fmaxf(sqrtf(s), EPS_);
  }
  __syncthreads();

  {
    float inv0 = invs[wn*48 +  0 + lc15];
    float inv1 = invs[wn*48 + 16 + lc15];
    float inv2 = invs[wn*48 + 32 + lc15];
    int cls    = wn*16 + lc15;
    int lcbase = ct * 32;
    #pragma unroll
    for (int m = 0; m < 4; ++m){
      #pragma unroll
      for (int r = 0; r < 4; ++r){
        int rl = wm*64 + m*16 + lhi*4 + r;
        float v = fmaxf(fmaxf(acc[m][0][r]*inv0, acc[m][1][r]*inv1), acc[m][2][r]*inv2);
        if (slab[rl] - lcbase == cls){
          float cy = v;
          float s2 = fminf(fmaxf(1.f - cy*cy, 0.f), 1.f);
          float sy = sqrtf(s2);
          float ph = cy*COSM_ - sy*SINM_;
          if (!(cy - TH_ > 0.f)) ph = cy - MM_;
          phi_g[rowbase + rl] = ph;
          v = ph;
        }
        sm.mx[rl*33 + cls] = v;
      }
    }
  }
  __syncthreads();

  {
    int row  = tid >> 1;
    int half = tid & 1;
    int grow = rowbase + row;
    float se = 0.f;
    u64 pk = 0ull;
    #pragma unroll
    for (int c = 0; c < 16; ++c){
      int lc = half*16 + c;
      float v = sm.mx[row*33 + lc];
      se += __expf(S_*v - S_);
      u32 u = __float_as_uint(v);
      u = (v >= 0.f) ? (u | 0x80000000u) : ~u;
      u64 p = ((u64)u << 32) | (u32)~(u32)(ct*32 + lc);
      pk = (p > pk) ? p : pk;
    }
    se += __shfl_xor(se, 1);
    u32 lo = (u32)pk, hi = (u32)(pk >> 32);
    u32 plo = __shfl_xor(lo, 1), phi2 = __shfl_xor(hi, 1);
    u64 po = ((u64)phi2 << 32) | plo;
    pk = (po > pk) ? po : pk;
    if (half == 0){
      atomicAdd(&sumexp_g[grow], se);
      atomicMax(&packed_g[grow], pk);
    }
  }
}

// ---------------- finalize: loss + prec1 ----------------
__global__ void k_final(const float* __restrict__ sumexp, const u64* __restrict__ packed,
                        const float* __restrict__ phi, const int* __restrict__ label,
                        float* __restrict__ out){
  int i = threadIdx.x;
  float lse  = S_ + logf(sumexp[i]);
  float loss = lse - S_ * phi[i];
  u32 pred = ~(u32)(packed[i] & 0xFFFFFFFFull);
  float corr = (pred == (u32)label[i]) ? 1.f : 0.f;
  float a = loss, b = corr;
  #pragma unroll
  for (int off = 1; off < 64; off <<= 1){ a += __shfl_xor(a, off); b += __shfl_xor(b, off); }
  __shared__ float sa[8], sb[8];
  if ((i & 63) == 0){ sa[i >> 6] = a; sb[i >> 6] = b; }
  __syncthreads();
  if (i == 0){
    float ta = 0.f, tb = 0.f;
    #pragma unroll
    for (int j = 0; j < 8; ++j){ ta += sa[j]; tb += sb[j]; }
    out[0] = ta / 512.f;
    out[1] = tb * (100.f / 512.f);
  }
}

extern "C" void kernel_launch(void* const* d_in, const int* in_sizes, int n_in,
                              void* d_out, int out_size, void* d_ws, size_t ws_size,
                              hipStream_t stream){
  const float* x     = (const float*)d_in[0];
  const int*   label = (const int*)d_in[1];
  const float* w     = (const float*)d_in[2];
  float* out = (float*)d_out;
  char* ws = (char*)d_ws;

  unsigned short* xn = (unsigned short*)ws;            // 524288 B
  float* sumexp = (float*)(ws + 524288);               // 2048 B
  u64*   packed = (u64*)(ws + 524288 + 2048);          // 4096 B
  float* phi    = (float*)(ws + 524288 + 2048 + 4096); // 2048 B
  unsigned short* wnb = (unsigned short*)(ws + 532480);// 307,200,000 B (Path A)

  const size_t needA = 532480ull + (size_t)CK_ * D_ * 2ull;

  k_init <<<1,   512, 0, stream>>>(sumexp, packed, phi);
  k_norm <<<B_/4, 256, 0, stream>>>(x, xn);
  if (ws_size >= needA){
    k_norm <<<CK_/4, 256, 0, stream>>>(w, wnb);
    k_gemm4<<<(CK_/BN)*4, 256, 0, stream>>>(xn, wnb, label, sumexp, packed, phi);
  } else {
    k_gemm_fused<<<(CK_/BN)*4, 256, 0, stream>>>(xn, w, label, sumexp, packed, phi);
  }
  k_final<<<1,   512, 0, stream>>>(sumexp, packed, phi, label, out);
}

// Round 7
// 393.815 us; speedup vs baseline: 2.2726x; 1.0401x over previous
//
#include <hip/hip_runtime.h>
#include <stdint.h>

#define B_ 512
#define D_ 512
#define C_ 100000
#define CK_ 300000
#define S_ 30.0f
#define COSM_ 0.8775825618903728f
#define SINM_ 0.4794255386042030f
#define TH_ (-0.8775825618903728f)
#define MM_ 0.2397127693021015f
#define EPS_ 1e-12f

#define BM 256
#define BN 96
#define BK 32
#define BUFU 14336   /* ushorts per buffer: A 256x32 bf16 (8192) + B 96x32 fp32 (6144) */

typedef float f32x4 __attribute__((ext_vector_type(4)));
typedef short s16x8 __attribute__((ext_vector_type(8)));
typedef unsigned long long u64;
typedef unsigned int u32;

#define GLL16(g, l) __builtin_amdgcn_global_load_lds( \
    (const __attribute__((address_space(1))) void*)(g), \
    (__attribute__((address_space(3))) void*)(l), 16, 0, 0)

__device__ __forceinline__ unsigned short f2bf(float f){
  u32 u = __float_as_uint(f);
  u += 0x7FFFu + ((u >> 16) & 1u);
  return (unsigned short)(u >> 16);
}

// ---------------- normalize x rows -> unit bf16 ----------------
__global__ void k_normx(const float* __restrict__ x, unsigned short* __restrict__ xn){
  int row  = blockIdx.x * 4 + (threadIdx.x >> 6);
  int lane = threadIdx.x & 63;
  const float* xr = x + (size_t)row * D_ + lane * 8;
  float4 v0 = *(const float4*)xr;
  float4 v1 = *(const float4*)(xr + 4);
  float s = v0.x*v0.x + v0.y*v0.y + v0.z*v0.z + v0.w*v0.w
          + v1.x*v1.x + v1.y*v1.y + v1.z*v1.z + v1.w*v1.w;
  #pragma unroll
  for (int off = 1; off < 64; off <<= 1) s += __shfl_xor(s, off);
  float inv = 1.f / fmaxf(sqrtf(s), EPS_);
  s16x8 h;
  h[0] = (short)f2bf(v0.x*inv); h[1] = (short)f2bf(v0.y*inv);
  h[2] = (short)f2bf(v0.z*inv); h[3] = (short)f2bf(v0.w*inv);
  h[4] = (short)f2bf(v1.x*inv); h[5] = (short)f2bf(v1.y*inv);
  h[6] = (short)f2bf(v1.z*inv); h[7] = (short)f2bf(v1.w*inv);
  *(s16x8*)(xn + (size_t)row * D_ + lane * 8) = h;
}

// ---------------- zero the per-row reduction buffers ----------------
__global__ void k_init(float* __restrict__ sumexp, u64* __restrict__ packed,
                       float* __restrict__ phi){
  int i = threadIdx.x;
  sumexp[i] = 0.f;
  packed[i] = 0ull;
  phi[i]    = 0.f;
}

// ======= single-pass fused GEMM: fp32 w DMA-staged, fragment-linear LDS =======
// A LDS: 16 frags (wm*8+m) x [lane][16B]  (bf16)
// B LDS: 6 frags (wn*3+n)  x [half][lane][16B]  (fp32; half = k 0-3 / 4-7 of lane's 8)
__global__ __launch_bounds__(256, 2) void k_gemm5(
    const unsigned short* __restrict__ xn, const float* __restrict__ w,
    const int* __restrict__ label,
    float* __restrict__ sumexp_g, u64* __restrict__ packed_g,
    float* __restrict__ phi_g)
{
  __shared__ unsigned short st[2*BUFU];   // 57344 B double-buffered
  __shared__ int slab[BM];
  float* mx = (float*)st;                 // epilogue overlay [256][33] = 33792 B

  // bijective XCD-chunked mapping: 6250 blocks = 8*781 + 2
  const int bid = blockIdx.x;
  const int xcd = bid & 7;
  const int i8  = bid >> 3;
  const int seq = (xcd < 2) ? (xcd*782 + i8) : (1564 + (xcd-2)*781 + i8);
  const int ct = seq >> 1;                 // column tile 0..3124 (32 classes each)
  const int rt = seq & 1;                  // row tile 0..1
  const int rowbase = rt * BM;
  const int lcbase  = ct * 32;

  const int tid  = threadIdx.x;
  const int lane = tid & 63;
  const int wid  = tid >> 6;
  const int wm   = wid >> 1, wn = wid & 1; // wave tile 128 rows x 48 cols
  const int lc15 = lane & 15, lhi = lane >> 4;

  slab[tid] = label[rowbase + tid];

  // ---- staging sources (kt-invariant). dest is always bufbase + pass*2048 + tid*8 (ushorts).
  // A pass p (0..3): frag fa = p*4 + wid; row = (fa>>3)*128 + (fa&7)*16 + (tid&15); k-slice (tid>>4)&3
  const unsigned short* asrc[4];
  #pragma unroll
  for (int p = 0; p < 4; ++p){
    int fa  = p*4 + wid;
    int row = rowbase + (fa >> 3)*128 + (fa & 7)*16 + (tid & 15);
    asrc[p] = xn + (size_t)row * D_ + ((tid >> 4) & 3) * 8;
  }
  // B pass p (0..2): frag fb = p*2 + (tid>>7) = wn_s*3 + n_s; half h = (tid>>6)&1
  const float* bsrc[3];
  #pragma unroll
  for (int p = 0; p < 3; ++p){
    int fb   = p*2 + (tid >> 7);
    int wn_s = fb / 3, n_s = fb % 3;
    int wrow = ct*96 + (wn_s*16 + (tid & 15))*3 + n_s;   // class (ct*32+wn_s*16+c), subcenter n_s
    bsrc[p]  = w + (size_t)wrow * D_ + ((tid >> 4) & 3)*8 + ((tid >> 6) & 1)*4;
  }

  // ---- fragment read offsets: ALL reads are base + lane*16B (conflict-free linear)
  int aroff[8];
  #pragma unroll
  for (int m = 0; m < 8; ++m) aroff[m] = (wm*8 + m)*512 + lane*8;   // ushort idx
  int bfoff[3];
  #pragma unroll
  for (int n = 0; n < 3; ++n) bfoff[n] = (wn*3 + n)*512 + lane*4;   // float idx

  f32x4 acc[8][3] = {};
  float sq[3] = {0.f, 0.f, 0.f};

  // ---- prologue: stage tile kt=0 into buffer 0 (7 loads/thread)
  #pragma unroll
  for (int p = 0; p < 4; ++p) GLL16(asrc[p], &st[p*2048 + tid*8]);
  #pragma unroll
  for (int p = 0; p < 3; ++p) GLL16(bsrc[p], &st[8192 + p*2048 + tid*8]);

#define STEP(CURB, NXTB, KT)                                                    \
  {                                                                             \
    if ((KT) < 15){                                                             \
      const int k1 = ((KT)+1)*BK;                                               \
      _Pragma("unroll")                                                         \
      for (int p = 0; p < 4; ++p) GLL16(asrc[p] + k1, &st[(NXTB) + p*2048 + tid*8]); \
      _Pragma("unroll")                                                         \
      for (int p = 0; p < 3; ++p) GLL16(bsrc[p] + k1, &st[(NXTB) + 8192 + p*2048 + tid*8]); \
      asm volatile("s_waitcnt vmcnt(7)" ::: "memory");                          \
    } else {                                                                    \
      asm volatile("s_waitcnt vmcnt(0)" ::: "memory");                          \
    }                                                                           \
    __builtin_amdgcn_s_barrier();                                               \
    asm volatile("" ::: "memory");                                              \
    const unsigned short* ab = &st[(CURB)];                                     \
    const float* bb = (const float*)&st[(CURB) + 8192];                         \
    s16x8 af[8];                                                                \
    _Pragma("unroll")                                                           \
    for (int m = 0; m < 8; ++m) af[m] = *(const s16x8*)(ab + aroff[m]);         \
    s16x8 bfr[3];                                                               \
    _Pragma("unroll")                                                           \
    for (int n = 0; n < 3; ++n){                                                \
      f32x4 b0 = *(const f32x4*)(bb + bfoff[n]);                                \
      f32x4 b1 = *(const f32x4*)(bb + bfoff[n] + 256);                          \
      sq[n] += b0[0]*b0[0] + b0[1]*b0[1] + b0[2]*b0[2] + b0[3]*b0[3]            \
             + b1[0]*b1[0] + b1[1]*b1[1] + b1[2]*b1[2] + b1[3]*b1[3];           \
      union { s16x8 h; u32 u[4]; } pk;                                          \
      asm("v_cvt_pk_bf16_f32 %0, %1, %2" : "=v"(pk.u[0]) : "v"(b0[0]), "v"(b0[1])); \
      asm("v_cvt_pk_bf16_f32 %0, %1, %2" : "=v"(pk.u[1]) : "v"(b0[2]), "v"(b0[3])); \
      asm("v_cvt_pk_bf16_f32 %0, %1, %2" : "=v"(pk.u[2]) : "v"(b1[0]), "v"(b1[1])); \
      asm("v_cvt_pk_bf16_f32 %0, %1, %2" : "=v"(pk.u[3]) : "v"(b1[2]), "v"(b1[3])); \
      bfr[n] = pk.h;                                                            \
    }                                                                           \
    _Pragma("unroll")                                                           \
    for (int m = 0; m < 8; ++m)                                                 \
      _Pragma("unroll")                                                         \
      for (int n = 0; n < 3; ++n)                                               \
        acc[m][n] = __builtin_amdgcn_mfma_f32_16x16x32_bf16(af[m], bfr[n], acc[m][n], 0, 0, 0); \
    asm volatile("" ::: "memory");                                              \
    __builtin_amdgcn_s_barrier();                                               \
  }

  for (int kt = 0; kt < 16; kt += 2){
    STEP(0,    BUFU, kt);
    STEP(BUFU, 0,    kt+1);
  }
#undef STEP

  // ---- weight-row inverse norms: fold lhi slices (exact fp32 sumsq)
  float inv[3];
  #pragma unroll
  for (int n = 0; n < 3; ++n){
    float s = sq[n];
    s += __shfl_xor(s, 16);
    s += __shfl_xor(s, 32);
    inv[n] = 1.f / fmaxf(sqrtf(s), EPS_);
  }

  // ---- subcenter max in-register; phi at label; write mx (overlay, post-barrier)
  {
    int cls = wn*16 + lc15;
    #pragma unroll
    for (int m = 0; m < 8; ++m){
      #pragma unroll
      for (int r = 0; r < 4; ++r){
        int rl = wm*128 + m*16 + lhi*4 + r;
        float v = fmaxf(fmaxf(acc[m][0][r]*inv[0], acc[m][1][r]*inv[1]), acc[m][2][r]*inv[2]);
        if (slab[rl] - lcbase == cls){
          float cy = v;
          float s2 = fminf(fmaxf(1.f - cy*cy, 0.f), 1.f);
          float sy = sqrtf(s2);
          float ph = cy*COSM_ - sy*SINM_;
          if (!(cy - TH_ > 0.f)) ph = cy - MM_;
          phi_g[rowbase + rl] = ph;        // unique writer
          v = ph;
        }
        mx[rl*33 + cls] = v;
      }
    }
  }
  __syncthreads();

  // ---- per-row LSE + argmax over this block's 32 classes: 1 thread per row
  {
    int grow = rowbase + tid;
    float se = 0.f;
    u64 pk = 0ull;
    #pragma unroll 8
    for (int lc = 0; lc < 32; ++lc){
      float v = mx[tid*33 + lc];
      se += __expf(S_*v - S_);
      u32 u = __float_as_uint(v);
      u = (v >= 0.f) ? (u | 0x80000000u) : ~u;            // sortable float
      u64 p = ((u64)u << 32) | (u32)~(u32)(lcbase + lc);  // ~idx: first-occurrence ties
      pk = (p > pk) ? p : pk;
    }
    atomicAdd(&sumexp_g[grow], se);
    atomicMax(&packed_g[grow], pk);
  }
}

// ---------------- finalize: loss + prec1 ----------------
__global__ void k_final(const float* __restrict__ sumexp, const u64* __restrict__ packed,
                        const float* __restrict__ phi, const int* __restrict__ label,
                        float* __restrict__ out){
  int i = threadIdx.x;
  float lse  = S_ + logf(sumexp[i]);
  float loss = lse - S_ * phi[i];
  u32 pred = ~(u32)(packed[i] & 0xFFFFFFFFull);
  float corr = (pred == (u32)label[i]) ? 1.f : 0.f;
  float a = loss, b = corr;
  #pragma unroll
  for (int off = 1; off < 64; off <<= 1){ a += __shfl_xor(a, off); b += __shfl_xor(b, off); }
  __shared__ float sa[8], sb[8];
  if ((i & 63) == 0){ sa[i >> 6] = a; sb[i >> 6] = b; }
  __syncthreads();
  if (i == 0){
    float ta = 0.f, tb = 0.f;
    #pragma unroll
    for (int j = 0; j < 8; ++j){ ta += sa[j]; tb += sb[j]; }
    out[0] = ta / 512.f;
    out[1] = tb * (100.f / 512.f);
  }
}

extern "C" void kernel_launch(void* const* d_in, const int* in_sizes, int n_in,
                              void* d_out, int out_size, void* d_ws, size_t ws_size,
                              hipStream_t stream){
  const float* x     = (const float*)d_in[0];
  const int*   label = (const int*)d_in[1];
  const float* w     = (const float*)d_in[2];
  float* out = (float*)d_out;
  char* ws = (char*)d_ws;

  unsigned short* xn = (unsigned short*)ws;            // 524288 B
  float* sumexp = (float*)(ws + 524288);               // 2048 B
  u64*   packed = (u64*)(ws + 524288 + 2048);          // 4096 B
  float* phi    = (float*)(ws + 524288 + 2048 + 4096); // 2048 B

  k_init <<<1,    512, 0, stream>>>(sumexp, packed, phi);
  k_normx<<<B_/4, 256, 0, stream>>>(x, xn);
  k_gemm5<<<(CK_/BN)*2, 256, 0, stream>>>(xn, w, label, sumexp, packed, phi);
  k_final<<<1,    512, 0, stream>>>(sumexp, packed, phi, label, out);
}

// Round 8
// 387.852 us; speedup vs baseline: 2.3076x; 1.0154x over previous
//
#include <hip/hip_runtime.h>
#include <stdint.h>

#define B_ 512
#define D_ 512
#define C_ 100000
#define CK_ 300000
#define S_ 30.0f
#define COSM_ 0.8775825618903728f
#define SINM_ 0.4794255386042030f
#define TH_ (-0.8775825618903728f)
#define MM_ 0.2397127693021015f
#define EPS_ 1e-12f

#define BM 128
#define BN 96
#define BK 32
#define BUFU 7168   /* ushorts per buffer: A 128x32 bf16 (4096) + B 96x32 bf16 (3072) */

typedef float f32x4 __attribute__((ext_vector_type(4)));
typedef short s16x8 __attribute__((ext_vector_type(8)));
typedef unsigned long long u64;
typedef unsigned int u32;

#define GLL16(g, l) __builtin_amdgcn_global_load_lds( \
    (const __attribute__((address_space(1))) void*)(g), \
    (__attribute__((address_space(3))) void*)(l), 16, 0, 0)

__device__ __forceinline__ unsigned short f2bf(float f){
  u32 u = __float_as_uint(f);
  u += 0x7FFFu + ((u >> 16) & 1u);
  return (unsigned short)(u >> 16);
}

// ---------------- normalize x rows -> unit bf16 ----------------
__global__ void k_normx(const float* __restrict__ x, unsigned short* __restrict__ xn){
  int row  = blockIdx.x * 4 + (threadIdx.x >> 6);
  int lane = threadIdx.x & 63;
  const float* xr = x + (size_t)row * D_ + lane * 8;
  float4 v0 = *(const float4*)xr;
  float4 v1 = *(const float4*)(xr + 4);
  float s = v0.x*v0.x + v0.y*v0.y + v0.z*v0.z + v0.w*v0.w
          + v1.x*v1.x + v1.y*v1.y + v1.z*v1.z + v1.w*v1.w;
  #pragma unroll
  for (int off = 1; off < 64; off <<= 1) s += __shfl_xor(s, off);
  float inv = 1.f / fmaxf(sqrtf(s), EPS_);
  s16x8 h;
  h[0] = (short)f2bf(v0.x*inv); h[1] = (short)f2bf(v0.y*inv);
  h[2] = (short)f2bf(v0.z*inv); h[3] = (short)f2bf(v0.w*inv);
  h[4] = (short)f2bf(v1.x*inv); h[5] = (short)f2bf(v1.y*inv);
  h[6] = (short)f2bf(v1.z*inv); h[7] = (short)f2bf(v1.w*inv);
  *(s16x8*)(xn + (size_t)row * D_ + lane * 8) = h;
}

// ---------------- zero the per-row reduction buffers ----------------
__global__ void k_init(float* __restrict__ sumexp, u64* __restrict__ packed,
                       float* __restrict__ phi){
  int i = threadIdx.x;
  sumexp[i] = 0.f;
  packed[i] = 0ull;
  phi[i]    = 0.f;
}

// ======= fused GEMM: A via gl_lds DMA, B reg-staged fp32->bf16, frag-linear LDS =======
__global__ __launch_bounds__(256, 4) void k_gemm6(
    const unsigned short* __restrict__ xn, const float* __restrict__ w,
    const int* __restrict__ label,
    float* __restrict__ sumexp_g, u64* __restrict__ packed_g,
    float* __restrict__ phi_g)
{
  __shared__ unsigned short st[2*BUFU];   // 28672 B double-buffered
  __shared__ float sqp[192];              // [fb 0..5][c 0..15][wv 0..1]
  __shared__ int   slab[BM];
  float* mx = (float*)st;                 // epilogue overlay [128][33]

  // bijective XCD-chunked mapping (12500 blocks = 8*1562 + 4)
  const int bid = blockIdx.x;
  const int xcd = bid & 7;
  const int i8  = bid >> 3;
  const int seq = (xcd < 4) ? (xcd*1563 + i8) : (6252 + (xcd-4)*1562 + i8);
  const int ct = seq >> 2;                 // column tile 0..3124
  const int rt = seq & 3;                  // row tile 0..3
  const int rowbase = rt * BM;
  const int lcbase  = ct * 32;

  const int tid  = threadIdx.x;
  const int lane = tid & 63;
  const int wid  = tid >> 6;
  const int wm   = wid >> 1, wn = wid & 1; // 2x2 wave grid, wave tile 64x48
  const int lc15 = lane & 15, lhi = lane >> 4;

  if (tid < BM) slab[tid] = label[rowbase + tid];

  // ---- A staging (gl_lds, 2 passes): frag fa = p*4+wid; lane l -> row fa*16+(l&15), k (l>>4)*8
  const unsigned short* asrc0;
  const unsigned short* asrc1;
  {
    int fa0 = wid,     row0 = rowbase + fa0*16 + (tid & 15);
    int fa1 = 4 + wid, row1 = rowbase + fa1*16 + (tid & 15);
    int koff = ((tid >> 4) & 3) * 8;
    asrc0 = xn + (size_t)row0 * D_ + koff;
    asrc1 = xn + (size_t)row1 * D_ + koff;
  }
  // ---- B staging (3 reg slots/thread): slot s=j*256+tid; fb=s>>7; rr=s&127; lb=rr>>1; hf=rr&1
  const float* bsrc0; const float* bsrc1; const float* bsrc2;
  int bdst0, bdst1, bdst2;
  {
    #define BSETUP(J, SRC, DST) { \
      int s  = (J)*256 + tid; \
      int fb = s >> 7, rr = s & 127; \
      int lb = rr >> 1, hf = rr & 1; \
      int wn_s = (fb >= 3), n_s = fb - wn_s*3; \
      int wrow = ct*BN + (wn_s*16 + (lb & 15))*3 + n_s; \
      SRC = w + (size_t)wrow * D_ + ((lb >> 4) & 3)*8 + hf*4; \
      DST = 4096 + fb*512 + lb*8 + hf*4; }
    BSETUP(0, bsrc0, bdst0)
    BSETUP(1, bsrc1, bdst1)
    BSETUP(2, bsrc2, bdst2)
    #undef BSETUP
  }

  // ---- fragment read offsets: base + lane*16B, conflict-free by construction
  int aoff[4], boff[3];
  #pragma unroll
  for (int m = 0; m < 4; ++m) aoff[m] = (wm*4 + m)*512 + lane*8;
  #pragma unroll
  for (int n = 0; n < 3; ++n) boff[n] = 4096 + (wn*3 + n)*512 + lane*8;

  f32x4 acc[4][3] = {};
  float sq0 = 0.f, sq1 = 0.f, sq2 = 0.f;

#define CVTW(BUFB, BV, DST, SQ) do{ \
    u32 _c0, _c1; \
    asm("v_cvt_pk_bf16_f32 %0, %1, %2" : "=v"(_c0) : "v"(BV.x), "v"(BV.y)); \
    asm("v_cvt_pk_bf16_f32 %0, %1, %2" : "=v"(_c1) : "v"(BV.z), "v"(BV.w)); \
    *(uint2*)(&st[(BUFB) + (DST)]) = make_uint2(_c0, _c1); \
    SQ += BV.x*BV.x + BV.y*BV.y + BV.z*BV.z + BV.w*BV.w; \
  }while(0)

  // ---- prologue: stage tile 0 into buffer 0
  {
    float4 b0 = *(const float4*)bsrc0;
    float4 b1 = *(const float4*)bsrc1;
    float4 b2 = *(const float4*)bsrc2;
    asm volatile("" ::: "memory");            // keep B issues before A gl_lds
    GLL16(asrc0, &st[tid*8]);
    GLL16(asrc1, &st[2048 + tid*8]);
    CVTW(0, b0, bdst0, sq0);
    CVTW(0, b1, bdst1, sq1);
    CVTW(0, b2, bdst2, sq2);
    asm volatile("s_waitcnt lgkmcnt(0)" ::: "memory");
  }

  // steady state vmem queue at step entry: [A(t):2] -> +B(t+1):3 +A(t+1):2 = 7
#define STEP(CURB, NXTB, KT) do{ \
    float4 b0_, b1_, b2_; \
    if ((KT) < 15){ \
      const int k1 = ((KT)+1)*BK; \
      b0_ = *(const float4*)(bsrc0 + k1); \
      b1_ = *(const float4*)(bsrc1 + k1); \
      b2_ = *(const float4*)(bsrc2 + k1); \
      asm volatile("" ::: "memory"); \
      GLL16(asrc0 + k1, &st[(NXTB) + tid*8]); \
      GLL16(asrc1 + k1, &st[(NXTB) + 2048 + tid*8]); \
      asm volatile("s_waitcnt vmcnt(5)" ::: "memory");  /* A(t) landed */ \
    } else { \
      asm volatile("s_waitcnt vmcnt(0)" ::: "memory"); \
    } \
    __builtin_amdgcn_s_barrier(); \
    asm volatile("" ::: "memory"); \
    { \
      const unsigned short* ab = &st[(CURB)]; \
      s16x8 af[4], bfr[3]; \
      _Pragma("unroll") \
      for (int m = 0; m < 4; ++m) af[m]  = *(const s16x8*)(ab + aoff[m]); \
      _Pragma("unroll") \
      for (int n = 0; n < 3; ++n) bfr[n] = *(const s16x8*)(ab + boff[n]); \
      _Pragma("unroll") \
      for (int m = 0; m < 4; ++m) \
        _Pragma("unroll") \
        for (int n = 0; n < 3; ++n) \
          acc[m][n] = __builtin_amdgcn_mfma_f32_16x16x32_bf16(af[m], bfr[n], acc[m][n], 0, 0, 0); \
    } \
    if ((KT) < 15){ \
      asm volatile("s_waitcnt vmcnt(2)" ::: "memory");  /* B(t+1) regs ready */ \
      CVTW(NXTB, b0_, bdst0, sq0); \
      CVTW(NXTB, b1_, bdst1, sq1); \
      CVTW(NXTB, b2_, bdst2, sq2); \
    } \
    asm volatile("s_waitcnt lgkmcnt(0)" ::: "memory"); \
    __builtin_amdgcn_s_barrier(); \
  }while(0)

  #pragma unroll
  for (int kt = 0; kt < 16; kt += 2){
    STEP(0,    BUFU, kt);
    STEP(BUFU, 0,    kt+1);
  }
#undef STEP
#undef CVTW

  // ---- weight-row sumsq: 4-way in-wave fold (partners ^1 = half, ^32 = lhi-bit), then LDS table
  sq0 += __shfl_xor(sq0, 1); sq0 += __shfl_xor(sq0, 32);
  sq1 += __shfl_xor(sq1, 1); sq1 += __shfl_xor(sq1, 32);
  sq2 += __shfl_xor(sq2, 1); sq2 += __shfl_xor(sq2, 32);
  if ((lane & 33) == 0){
    int c  = (tid >> 1) & 15;
    int hi = tid >> 7;
    int wv = (tid >> 6) & 1;
    sqp[(0 + hi)*32 + c*2 + wv] = sq0;
    sqp[(2 + hi)*32 + c*2 + wv] = sq1;
    sqp[(4 + hi)*32 + c*2 + wv] = sq2;
  }
  __syncthreads();

  float inv_[3];
  #pragma unroll
  for (int n = 0; n < 3; ++n){
    int fb = wn*3 + n;
    float s = sqp[fb*32 + lc15*2] + sqp[fb*32 + lc15*2 + 1];
    inv_[n] = 1.f / fmaxf(sqrtf(s), EPS_);
  }

  // ---- subcenter max in-register; phi at label; write mx (overlay)
  {
    int cls = wn*16 + lc15;
    #pragma unroll
    for (int m = 0; m < 4; ++m){
      #pragma unroll
      for (int r = 0; r < 4; ++r){
        int rl = wm*64 + m*16 + lhi*4 + r;
        float v = fmaxf(fmaxf(acc[m][0][r]*inv_[0], acc[m][1][r]*inv_[1]), acc[m][2][r]*inv_[2]);
        if (slab[rl] - lcbase == cls){
          float cy = v;
          float s2 = fminf(fmaxf(1.f - cy*cy, 0.f), 1.f);
          float sy = sqrtf(s2);
          float ph = cy*COSM_ - sy*SINM_;
          if (!(cy - TH_ > 0.f)) ph = cy - MM_;
          phi_g[rowbase + rl] = ph;        // unique writer
          v = ph;
        }
        mx[rl*33 + cls] = v;
      }
    }
  }
  __syncthreads();

  // ---- per-row LSE + argmax over this block's 32 classes: 2 threads per row
  {
    int row  = tid >> 1;
    int half = tid & 1;
    int grow = rowbase + row;
    float se = 0.f;
    u64 pk = 0ull;
    #pragma unroll
    for (int c = 0; c < 16; ++c){
      int lc = half*16 + c;
      float v = mx[row*33 + lc];
      se += __expf(S_*v - S_);
      u32 u = __float_as_uint(v);
      u = (v >= 0.f) ? (u | 0x80000000u) : ~u;            // sortable float
      u64 p = ((u64)u << 32) | (u32)~(u32)(lcbase + lc);  // ~idx: first-occurrence ties
      pk = (p > pk) ? p : pk;
    }
    se += __shfl_xor(se, 1);
    u32 lo = (u32)pk, hi2 = (u32)(pk >> 32);
    u32 plo = __shfl_xor(lo, 1), phi2 = __shfl_xor(hi2, 1);
    u64 po = ((u64)phi2 << 32) | plo;
    pk = (po > pk) ? po : pk;
    if (half == 0){
      atomicAdd(&sumexp_g[grow], se);
      atomicMax(&packed_g[grow], pk);
    }
  }
}

// ---------------- finalize: loss + prec1 ----------------
__global__ void k_final(const float* __restrict__ sumexp, const u64* __restrict__ packed,
                        const float* __restrict__ phi, const int* __restrict__ label,
                        float* __restrict__ out){
  int i = threadIdx.x;
  float lse  = S_ + logf(sumexp[i]);
  float loss = lse - S_ * phi[i];
  u32 pred = ~(u32)(packed[i] & 0xFFFFFFFFull);
  float corr = (pred == (u32)label[i]) ? 1.f : 0.f;
  float a = loss, b = corr;
  #pragma unroll
  for (int off = 1; off < 64; off <<= 1){ a += __shfl_xor(a, off); b += __shfl_xor(b, off); }
  __shared__ float sa[8], sb[8];
  if ((i & 63) == 0){ sa[i >> 6] = a; sb[i >> 6] = b; }
  __syncthreads();
  if (i == 0){
    float ta = 0.f, tb = 0.f;
    #pragma unroll
    for (int j = 0; j < 8; ++j){ ta += sa[j]; tb += sb[j]; }
    out[0] = ta / 512.f;
    out[1] = tb * (100.f / 512.f);
  }
}

extern "C" void kernel_launch(void* const* d_in, const int* in_sizes, int n_in,
                              void* d_out, int out_size, void* d_ws, size_t ws_size,
                              hipStream_t stream){
  const float* x     = (const float*)d_in[0];
  const int*   label = (const int*)d_in[1];
  const float* w     = (const float*)d_in[2];
  float* out = (float*)d_out;
  char* ws = (char*)d_ws;

  unsigned short* xn = (unsigned short*)ws;            // 524288 B
  float* sumexp = (float*)(ws + 524288);               // 2048 B
  u64*   packed = (u64*)(ws + 524288 + 2048);          // 4096 B
  float* phi    = (float*)(ws + 524288 + 2048 + 4096); // 2048 B

  k_init <<<1,    512, 0, stream>>>(sumexp, packed, phi);
  k_normx<<<B_/4, 256, 0, stream>>>(x, xn);
  k_gemm6<<<(CK_/BN)*4, 256, 0, stream>>>(xn, w, label, sumexp, packed, phi);
  k_final<<<1,    512, 0, stream>>>(sumexp, packed, phi, label, out);
}